// Round 11
// baseline (160.357 us; speedup 1.0000x reference)
//
#include <hip/hip_runtime.h>

#define D 64
#define NB_SHIFT 9          // 512 nodes per bucket
#define NODES_PER_B 512
#define CAP1 12288          // max edges per bucket (mean ~5120)

typedef __attribute__((ext_vector_type(8))) short short8;
typedef __attribute__((ext_vector_type(4))) float f32x4;

__device__ inline unsigned short f2bf(float f) {
    unsigned int u = __float_as_uint(f);
    return (unsigned short)((u + 0x7FFFu + ((u >> 16) & 1u)) >> 16);  // RNE
}
__device__ inline float bf2f(unsigned short s) {
    return __uint_as_float(((unsigned int)s) << 16);
}

// ---------------------------------------------------------------------------
// Prep: fp32->bf16 convert of x, weight pack (4 matrices), gcount zero.
// ---------------------------------------------------------------------------
__global__ __launch_bounds__(256) void prep_kernel(
        const float* __restrict__ x, unsigned short* __restrict__ xb, int n4,
        const float* __restrict__ W1l, const float* __restrict__ W1r,
        const float* __restrict__ W2l, const float* __restrict__ W2r,
        unsigned short* __restrict__ pw, int* __restrict__ gcount) {
    int gid = blockIdx.x * blockDim.x + threadIdx.x;
    int stride = gridDim.x * blockDim.x;
    for (int t = gid; t < n4; t += stride) {
        float4 v = ((const float4*)x)[t];
        ushort4 o;
        o.x = f2bf(v.x); o.y = f2bf(v.y); o.z = f2bf(v.z); o.w = f2bf(v.w);
        ((ushort4*)xb)[t] = o;
    }
    if (gid < 4 * 4096) {
        int m = gid >> 12;
        int r = gid & 4095;
        const float* W = (m == 0) ? W1l : (m == 1) ? W1r : (m == 2) ? W2l : W2r;
        int j    = r & 7;
        int lane = (r >> 3) & 63;
        int kk   = (r >> 9) & 1;
        int ct   = r >> 10;
        int k    = kk * 32 + ((lane >> 4) & 3) * 8 + j;
        int col  = ct * 16 + (lane & 15);
        pw[gid] = f2bf(W[k * D + col]);
    } else if (gid < 4 * 4096 + 256) {
        gcount[gid - 4 * 4096] = 0;
    }
}

// ---------------------------------------------------------------------------
// Pass 1: bin edges by dst bucket (dst>>9). int4-vectorized loads.
// Payload packed: (src<<9)|dst_low.
// ---------------------------------------------------------------------------
__global__ __launch_bounds__(256) void bin_edges_kernel(
        const int* __restrict__ src, const int* __restrict__ dst,
        int* __restrict__ gcount, int* __restrict__ binned,
        int n_edges, int n_buckets) {
    __shared__ int lhist[256];
    __shared__ int lbase[256];
    int tid = threadIdx.x;
    // per-block chunk, 4-aligned start
    int per = (((n_edges + gridDim.x - 1) / gridDim.x) + 3) & ~3;
    int beg = blockIdx.x * per;
    int end = min(beg + per, n_edges);
    if (beg >= end) { return; }
    int nv = (end - beg) >> 2;
    const int4* d4p = (const int4*)(dst + beg);
    const int4* s4p = (const int4*)(src + beg);

    lhist[tid] = 0;
    __syncthreads();
    for (int i = tid; i < nv; i += 256) {
        int4 d4 = d4p[i];
        atomicAdd(&lhist[d4.x >> NB_SHIFT], 1);
        atomicAdd(&lhist[d4.y >> NB_SHIFT], 1);
        atomicAdd(&lhist[d4.z >> NB_SHIFT], 1);
        atomicAdd(&lhist[d4.w >> NB_SHIFT], 1);
    }
    for (int e = beg + (nv << 2) + tid; e < end; e += 256)
        atomicAdd(&lhist[dst[e] >> NB_SHIFT], 1);
    __syncthreads();
    if (tid < n_buckets && lhist[tid] > 0)
        lbase[tid] = atomicAdd(&gcount[tid], lhist[tid]);
    else
        lbase[tid] = 0;
    __syncthreads();
    lhist[tid] = 0;   // reuse as running cursor
    __syncthreads();
    for (int i = tid; i < nv; i += 256) {
        int4 d4 = d4p[i];
        int4 s4 = s4p[i];
        {
            int b = d4.x >> NB_SHIFT;
            int off = lbase[b] + atomicAdd(&lhist[b], 1);
            if (off < CAP1)
                binned[(size_t)b * CAP1 + off] = (s4.x << NB_SHIFT) | (d4.x & (NODES_PER_B - 1));
        }
        {
            int b = d4.y >> NB_SHIFT;
            int off = lbase[b] + atomicAdd(&lhist[b], 1);
            if (off < CAP1)
                binned[(size_t)b * CAP1 + off] = (s4.y << NB_SHIFT) | (d4.y & (NODES_PER_B - 1));
        }
        {
            int b = d4.z >> NB_SHIFT;
            int off = lbase[b] + atomicAdd(&lhist[b], 1);
            if (off < CAP1)
                binned[(size_t)b * CAP1 + off] = (s4.z << NB_SHIFT) | (d4.z & (NODES_PER_B - 1));
        }
        {
            int b = d4.w >> NB_SHIFT;
            int off = lbase[b] + atomicAdd(&lhist[b], 1);
            if (off < CAP1)
                binned[(size_t)b * CAP1 + off] = (s4.w << NB_SHIFT) | (d4.w & (NODES_PER_B - 1));
        }
    }
    for (int e = beg + (nv << 2) + tid; e < end; e += 256) {
        int d = dst[e];
        int b = d >> NB_SHIFT;
        int off = lbase[b] + atomicAdd(&lhist[b], 1);
        if (off < CAP1)
            binned[(size_t)b * CAP1 + off] = (src[e] << NB_SHIFT) | (d & (NODES_PER_B - 1));
    }
}

// ---------------------------------------------------------------------------
// Pass 2: one block per bucket. Inline bucket-count scan -> base; local degree
// histogram -> LDS scan -> coalesced rowp + ssrc.
// ---------------------------------------------------------------------------
__global__ __launch_bounds__(256) void build_csr_kernel(
        const int* __restrict__ binned, const int* __restrict__ gcount,
        int* __restrict__ rowp, int* __restrict__ ssrc,
        int n_nodes, int n_buckets, int n_edges) {
    __shared__ int lhist[NODES_PER_B];
    __shared__ int lbase[NODES_PER_B];
    __shared__ int tmp[256];
    __shared__ int stage[CAP1];

    int b   = blockIdx.x;
    int tid = threadIdx.x;

    int v = (tid < n_buckets) ? min(gcount[tid], CAP1) : 0;
    tmp[tid] = v;
    __syncthreads();
    for (int off = 1; off < 256; off <<= 1) {
        int t = 0;
        if (tid >= off) t = tmp[tid - off];
        __syncthreads();
        if (tid >= off) tmp[tid] += t;
        __syncthreads();
    }
    int base = (b == 0) ? 0 : tmp[b - 1];
    int cnt  = min(gcount[b], CAP1);
    if (b == 0 && tid == 0) rowp[n_nodes] = n_edges;
    __syncthreads();

    int nodebase = b << NB_SHIFT;
    int nlocal   = min(NODES_PER_B, n_nodes - nodebase);
    const int* ebuf = binned + (size_t)b * CAP1;

    lhist[tid] = 0;
    lhist[tid + 256] = 0;
    __syncthreads();
    for (int i = tid; i < cnt; i += 256)
        atomicAdd(&lhist[ebuf[i] & (NODES_PER_B - 1)], 1);
    __syncthreads();

    int a0 = lhist[2 * tid];
    int a1 = lhist[2 * tid + 1];
    tmp[tid] = a0 + a1;
    __syncthreads();
    for (int off = 1; off < 256; off <<= 1) {
        int t = 0;
        if (tid >= off) t = tmp[tid - off];
        __syncthreads();
        if (tid >= off) tmp[tid] += t;
        __syncthreads();
    }
    int excl = tmp[tid] - (a0 + a1);
    lbase[2 * tid]     = excl;
    lbase[2 * tid + 1] = excl + a0;
    __syncthreads();

    for (int j = tid; j < nlocal; j += 256)
        rowp[nodebase + j] = base + lbase[j];

    lhist[tid] = 0;
    lhist[tid + 256] = 0;
    __syncthreads();

    for (int i = tid; i < cnt; i += 256) {
        int e  = ebuf[i];
        int ln = e & (NODES_PER_B - 1);
        int off = atomicAdd(&lhist[ln], 1);
        stage[lbase[ln] + off] = e >> NB_SHIFT;
    }
    __syncthreads();

    for (int i = tid; i < cnt; i += 256)
        ssrc[base + i] = stage[i];
}

// ---------------------------------------------------------------------------
// Mean aggregation v5: wave per node, contiguous node chunk per wave.
// Lane = (row-group r = lane>>4, dim-quad c = lane&15). 32 edges/iter via
// 8 ushort4 gather loads in flight (single iteration for deg<=32, ~all
// nodes at Poisson(10)). Clamped slots broadcast one row (cheap).
// 2-stage butterfly; 16 lanes write row.
// ---------------------------------------------------------------------------
__global__ __launch_bounds__(256) void aggregate_bf16_kernel(
        const unsigned short* __restrict__ feat,
        const int* __restrict__ row_ptr,
        const int* __restrict__ sorted_src,
        unsigned short* __restrict__ mean_out,
        int n_nodes) {
    int lane = threadIdx.x & 63;
    int r    = lane >> 4;
    int c    = lane & 15;
    int wave   = (int)((blockIdx.x * blockDim.x + threadIdx.x) >> 6);
    int nwaves = (int)((gridDim.x * blockDim.x) >> 6);
    int npw  = (n_nodes + nwaves - 1) / nwaves;
    int nbeg = wave * npw;
    int nend = min(nbeg + npw, n_nodes);
    if (nbeg >= nend) return;

    int beg = row_ptr[nbeg];
    for (int node = nbeg; node < nend; ++node) {
        int end = row_ptr[node + 1];
        int endm1 = end - 1;
        float a0 = 0.f, a1 = 0.f, a2 = 0.f, a3 = 0.f;

        for (int i = beg; i < end; i += 32) {
            int e0 = i + r,      e1 = i + 4 + r,  e2 = i + 8 + r,  e3 = i + 12 + r;
            int e4 = i + 16 + r, e5 = i + 20 + r, e6 = i + 24 + r, e7 = i + 28 + r;
            int s0 = sorted_src[min(e0, endm1)];
            int s1 = sorted_src[min(e1, endm1)];
            int s2 = sorted_src[min(e2, endm1)];
            int s3 = sorted_src[min(e3, endm1)];
            int s4 = sorted_src[min(e4, endm1)];
            int s5 = sorted_src[min(e5, endm1)];
            int s6 = sorted_src[min(e6, endm1)];
            int s7 = sorted_src[min(e7, endm1)];
            ushort4 v0 = *(const ushort4*)(feat + ((size_t)s0 << 6) + (c << 2));
            ushort4 v1 = *(const ushort4*)(feat + ((size_t)s1 << 6) + (c << 2));
            ushort4 v2 = *(const ushort4*)(feat + ((size_t)s2 << 6) + (c << 2));
            ushort4 v3 = *(const ushort4*)(feat + ((size_t)s3 << 6) + (c << 2));
            ushort4 v4 = *(const ushort4*)(feat + ((size_t)s4 << 6) + (c << 2));
            ushort4 v5 = *(const ushort4*)(feat + ((size_t)s5 << 6) + (c << 2));
            ushort4 v6 = *(const ushort4*)(feat + ((size_t)s6 << 6) + (c << 2));
            ushort4 v7 = *(const ushort4*)(feat + ((size_t)s7 << 6) + (c << 2));
            if (e0 < end) { a0 += bf2f(v0.x); a1 += bf2f(v0.y); a2 += bf2f(v0.z); a3 += bf2f(v0.w); }
            if (e1 < end) { a0 += bf2f(v1.x); a1 += bf2f(v1.y); a2 += bf2f(v1.z); a3 += bf2f(v1.w); }
            if (e2 < end) { a0 += bf2f(v2.x); a1 += bf2f(v2.y); a2 += bf2f(v2.z); a3 += bf2f(v2.w); }
            if (e3 < end) { a0 += bf2f(v3.x); a1 += bf2f(v3.y); a2 += bf2f(v3.z); a3 += bf2f(v3.w); }
            if (e4 < end) { a0 += bf2f(v4.x); a1 += bf2f(v4.y); a2 += bf2f(v4.z); a3 += bf2f(v4.w); }
            if (e5 < end) { a0 += bf2f(v5.x); a1 += bf2f(v5.y); a2 += bf2f(v5.z); a3 += bf2f(v5.w); }
            if (e6 < end) { a0 += bf2f(v6.x); a1 += bf2f(v6.y); a2 += bf2f(v6.z); a3 += bf2f(v6.w); }
            if (e7 < end) { a0 += bf2f(v7.x); a1 += bf2f(v7.y); a2 += bf2f(v7.z); a3 += bf2f(v7.w); }
        }
        a0 += __shfl_xor(a0, 16); a1 += __shfl_xor(a1, 16);
        a2 += __shfl_xor(a2, 16); a3 += __shfl_xor(a3, 16);
        a0 += __shfl_xor(a0, 32); a1 += __shfl_xor(a1, 32);
        a2 += __shfl_xor(a2, 32); a3 += __shfl_xor(a3, 32);

        float inv = 1.0f / (float)max(end - beg, 1);
        if (r == 0) {
            ushort4 o;
            o.x = f2bf(a0 * inv); o.y = f2bf(a1 * inv);
            o.z = f2bf(a2 * inv); o.w = f2bf(a3 * inv);
            *(ushort4*)(mean_out + ((size_t)node << 6) + (c << 2)) = o;
        }
        beg = end;
    }
}

// ---------------------------------------------------------------------------
// Fused SAGE linear on MFMA: out = [relu]( mean @ Wl + xin @ Wr + b ), bf16 io.
// Grid sized so each wave handles exactly 2 tiles (balanced).
// ---------------------------------------------------------------------------
__global__ __launch_bounds__(256) void sage_linear_mfma_kernel(
        const unsigned short* __restrict__ mean,
        const unsigned short* __restrict__ xin,
        const unsigned short* __restrict__ pwl,
        const unsigned short* __restrict__ pwr,
        const float* __restrict__ bias,
        unsigned short* __restrict__ outp,
        int n_nodes, int do_relu) {
    int lane = threadIdx.x & 63;
    int wid  = threadIdx.x >> 6;
    int arow = lane & 15;
    int kgrp = lane >> 4;

    short8 wl[4][2], wr[4][2];
#pragma unroll
    for (int ct = 0; ct < 4; ++ct)
#pragma unroll
        for (int kk = 0; kk < 2; ++kk) {
            wl[ct][kk] = *(const short8*)(pwl + (((ct * 2 + kk) * 64 + lane) << 3));
            wr[ct][kk] = *(const short8*)(pwr + (((ct * 2 + kk) * 64 + lane) << 3));
        }
    float bj[4];
#pragma unroll
    for (int ct = 0; ct < 4; ++ct) bj[ct] = bias[ct * 16 + arow];

    int wave   = blockIdx.x * 4 + wid;
    int nwaves = gridDim.x * 4;
    int ntiles = (n_nodes + 15) >> 4;

    for (int t = wave; t < ntiles; t += nwaves) {
        int base = t * 16;
        int lrow = base + arow;
        if (lrow >= n_nodes) lrow = n_nodes - 1;
        const unsigned short* mrow = mean + (size_t)lrow * D + kgrp * 8;
        const unsigned short* xrow = xin  + (size_t)lrow * D + kgrp * 8;
        short8 am0 = *(const short8*)(mrow);
        short8 am1 = *(const short8*)(mrow + 32);
        short8 ax0 = *(const short8*)(xrow);
        short8 ax1 = *(const short8*)(xrow + 32);

#pragma unroll
        for (int ct = 0; ct < 4; ++ct) {
            f32x4 acc = {0.f, 0.f, 0.f, 0.f};
            acc = __builtin_amdgcn_mfma_f32_16x16x32_bf16(am0, wl[ct][0], acc, 0, 0, 0);
            acc = __builtin_amdgcn_mfma_f32_16x16x32_bf16(am1, wl[ct][1], acc, 0, 0, 0);
            acc = __builtin_amdgcn_mfma_f32_16x16x32_bf16(ax0, wr[ct][0], acc, 0, 0, 0);
            acc = __builtin_amdgcn_mfma_f32_16x16x32_bf16(ax1, wr[ct][1], acc, 0, 0, 0);
            int col = ct * 16 + arow;
#pragma unroll
            for (int rr = 0; rr < 4; ++rr) {
                int row = base + kgrp * 4 + rr;
                float v = acc[rr] + bj[ct];
                if (do_relu) v = fmaxf(v, 0.0f);
                if (row < n_nodes) outp[(size_t)row * D + col] = f2bf(v);
            }
        }
    }
}

// ---------------------------------------------------------------------------
// Edge decode: 16-lane group per edge, 2 edges per group per iteration
// (8 edges/wave-iter, 4 row-pair loads in flight per lane).
// ---------------------------------------------------------------------------
__global__ __launch_bounds__(256) void decode_bf16_kernel(
        const unsigned short* __restrict__ z,
        const int* __restrict__ esrc,
        const int* __restrict__ edst,
        float* __restrict__ out,
        int n) {
    int lane = threadIdx.x & 63;
    int g    = lane >> 4;
    int c    = lane & 15;
    int wave   = (int)((blockIdx.x * blockDim.x + threadIdx.x) >> 6);
    int nwaves = (int)((gridDim.x * blockDim.x) >> 6);
    int niter  = (n + 7) >> 3;

    for (int it = wave; it < niter; it += nwaves) {
        int e0 = it * 8 + g;
        int e1 = it * 8 + 4 + g;
        int ec0 = min(e0, n - 1);
        int ec1 = min(e1, n - 1);
        int s0  = esrc[ec0], d0 = edst[ec0];
        int s1  = esrc[ec1], d1 = edst[ec1];
        ushort4 vs0 = *(const ushort4*)(z + ((size_t)s0 << 6) + (c << 2));
        ushort4 vd0 = *(const ushort4*)(z + ((size_t)d0 << 6) + (c << 2));
        ushort4 vs1 = *(const ushort4*)(z + ((size_t)s1 << 6) + (c << 2));
        ushort4 vd1 = *(const ushort4*)(z + ((size_t)d1 << 6) + (c << 2));
        float p0 = bf2f(vs0.x) * bf2f(vd0.x) + bf2f(vs0.y) * bf2f(vd0.y) +
                   bf2f(vs0.z) * bf2f(vd0.z) + bf2f(vs0.w) * bf2f(vd0.w);
        float p1 = bf2f(vs1.x) * bf2f(vd1.x) + bf2f(vs1.y) * bf2f(vd1.y) +
                   bf2f(vs1.z) * bf2f(vd1.z) + bf2f(vs1.w) * bf2f(vd1.w);
        p0 += __shfl_xor(p0, 1);  p1 += __shfl_xor(p1, 1);
        p0 += __shfl_xor(p0, 2);  p1 += __shfl_xor(p1, 2);
        p0 += __shfl_xor(p0, 4);  p1 += __shfl_xor(p1, 4);
        p0 += __shfl_xor(p0, 8);  p1 += __shfl_xor(p1, 8);
        if (c == 0 && e0 < n) out[e0] = p0;
        if (c == 0 && e1 < n) out[e1] = p1;
    }
}

extern "C" void kernel_launch(void* const* d_in, const int* in_sizes, int n_in,
                              void* d_out, int out_size, void* d_ws, size_t ws_size,
                              hipStream_t stream) {
    const float* x   = (const float*)d_in[0];
    const int*   ei  = (const int*)d_in[1];   // [2, E]: src row then dst row
    const int*   eli = (const int*)d_in[2];   // [2, L]
    const float* W1l = (const float*)d_in[3];
    const float* W1r = (const float*)d_in[4];
    const float* b1  = (const float*)d_in[5];
    const float* W2l = (const float*)d_in[6];
    const float* W2r = (const float*)d_in[7];
    const float* b2  = (const float*)d_in[8];
    float* out = (float*)d_out;

    const int n_nodes = in_sizes[0] / D;
    const int n_edges = in_sizes[1] / 2;
    const int n_label = in_sizes[2] / 2;
    const int n_buckets = (n_nodes + NODES_PER_B - 1) >> NB_SHIFT;

    const int* e_src = ei;
    const int* e_dst = ei + n_edges;
    const int* l_src = eli;
    const int* l_dst = eli + n_label;

    // Workspace layout:
    //   xb, meanb, h, z : N*64 ushort each
    //   rowp : N+1 ints; ssrc : E + 8 ints
    //   gcount : 256 ints; pw : 4*4096 ushort
    //   binned (packed ints, ~9.6 MB) aliases h (dead until L1 linear writes h)
    unsigned short* xb    = (unsigned short*)d_ws;
    unsigned short* meanb = xb + (size_t)n_nodes * D;
    unsigned short* h     = meanb + (size_t)n_nodes * D;
    unsigned short* z     = h + (size_t)n_nodes * D;
    int* rowp   = (int*)(z + (size_t)n_nodes * D);
    int* ssrc   = rowp + (n_nodes + 1);
    int* gcount = ssrc + n_edges + 8;
    unsigned short* pw = (unsigned short*)(gcount + 256);
    unsigned short* pw1l = pw;
    unsigned short* pw1r = pw + 4096;
    unsigned short* pw2l = pw + 8192;
    unsigned short* pw2r = pw + 12288;
    int* binned = (int*)h;

    dim3 blk(256);
    dim3 grd_nodes(2048);
    dim3 grd_linear(782);   // 3128 waves x 2 tiles = 6256 >= 6250 tiles, balanced

    // ---- Prep (convert + pack + gcount zero) ----
    prep_kernel<<<dim3(2048), blk, 0, stream>>>(x, xb, n_nodes * D / 4,
                                                W1l, W1r, W2l, W2r, pw, gcount);

    // ---- CSR build ----
    bin_edges_kernel<<<dim3(512), blk, 0, stream>>>(e_src, e_dst, gcount, binned,
                                                    n_edges, n_buckets);
    build_csr_kernel<<<dim3(n_buckets), blk, 0, stream>>>(binned, gcount, rowp,
                                                          ssrc, n_nodes,
                                                          n_buckets, n_edges);

    // ---- Layer 1 ----
    aggregate_bf16_kernel<<<grd_nodes, blk, 0, stream>>>(xb, rowp, ssrc, meanb, n_nodes);
    sage_linear_mfma_kernel<<<grd_linear, blk, 0, stream>>>(meanb, xb, pw1l, pw1r, b1,
                                                            h, n_nodes, /*relu=*/1);

    // ---- Layer 2 ----
    aggregate_bf16_kernel<<<grd_nodes, blk, 0, stream>>>(h, rowp, ssrc, meanb, n_nodes);
    sage_linear_mfma_kernel<<<grd_linear, blk, 0, stream>>>(meanb, h, pw2l, pw2r, b2,
                                                            z, n_nodes, /*relu=*/0);

    // ---- Decode ----
    decode_bf16_kernel<<<dim3(2048), blk, 0, stream>>>(z, l_src, l_dst, out, n_label);
}

// Round 12
// 136.076 us; speedup vs baseline: 1.1784x; 1.1784x over previous
//
#include <hip/hip_runtime.h>

#define D 64
#define NB_SHIFT 9          // 512 nodes per bucket
#define NODES_PER_B 512
#define CAP1 12288          // max edges per bucket (mean ~5120)

typedef __attribute__((ext_vector_type(8))) short short8;
typedef __attribute__((ext_vector_type(4))) float f32x4;

__device__ inline unsigned short f2bf(float f) {
    unsigned int u = __float_as_uint(f);
    return (unsigned short)((u + 0x7FFFu + ((u >> 16) & 1u)) >> 16);  // RNE
}
__device__ inline float bf2f(unsigned short s) {
    return __uint_as_float(((unsigned int)s) << 16);
}

// ---------------------------------------------------------------------------
// Prep: fp32->bf16 convert of x, weight pack (4 matrices), gcount zero.
// ---------------------------------------------------------------------------
__global__ __launch_bounds__(256) void prep_kernel(
        const float* __restrict__ x, unsigned short* __restrict__ xb, int n4,
        const float* __restrict__ W1l, const float* __restrict__ W1r,
        const float* __restrict__ W2l, const float* __restrict__ W2r,
        unsigned short* __restrict__ pw, int* __restrict__ gcount) {
    int gid = blockIdx.x * blockDim.x + threadIdx.x;
    int stride = gridDim.x * blockDim.x;
    for (int t = gid; t < n4; t += stride) {
        float4 v = ((const float4*)x)[t];
        ushort4 o;
        o.x = f2bf(v.x); o.y = f2bf(v.y); o.z = f2bf(v.z); o.w = f2bf(v.w);
        ((ushort4*)xb)[t] = o;
    }
    if (gid < 4 * 4096) {
        int m = gid >> 12;
        int r = gid & 4095;
        const float* W = (m == 0) ? W1l : (m == 1) ? W1r : (m == 2) ? W2l : W2r;
        int j    = r & 7;
        int lane = (r >> 3) & 63;
        int kk   = (r >> 9) & 1;
        int ct   = r >> 10;
        int k    = kk * 32 + ((lane >> 4) & 3) * 8 + j;
        int col  = ct * 16 + (lane & 15);
        pw[gid] = f2bf(W[k * D + col]);
    } else if (gid < 4 * 4096 + 256) {
        gcount[gid - 4 * 4096] = 0;
    }
}

// ---------------------------------------------------------------------------
// Pass 1: bin edges by dst bucket (dst>>9). int4-vectorized loads.
// Payload packed: (src<<9)|dst_low.
// ---------------------------------------------------------------------------
__global__ __launch_bounds__(256) void bin_edges_kernel(
        const int* __restrict__ src, const int* __restrict__ dst,
        int* __restrict__ gcount, int* __restrict__ binned,
        int n_edges, int n_buckets) {
    __shared__ int lhist[256];
    __shared__ int lbase[256];
    int tid = threadIdx.x;
    // per-block chunk, 4-aligned start
    int per = (((n_edges + gridDim.x - 1) / gridDim.x) + 3) & ~3;
    int beg = blockIdx.x * per;
    int end = min(beg + per, n_edges);
    if (beg >= end) { return; }
    int nv = (end - beg) >> 2;
    const int4* d4p = (const int4*)(dst + beg);
    const int4* s4p = (const int4*)(src + beg);

    lhist[tid] = 0;
    __syncthreads();
    for (int i = tid; i < nv; i += 256) {
        int4 d4 = d4p[i];
        atomicAdd(&lhist[d4.x >> NB_SHIFT], 1);
        atomicAdd(&lhist[d4.y >> NB_SHIFT], 1);
        atomicAdd(&lhist[d4.z >> NB_SHIFT], 1);
        atomicAdd(&lhist[d4.w >> NB_SHIFT], 1);
    }
    for (int e = beg + (nv << 2) + tid; e < end; e += 256)
        atomicAdd(&lhist[dst[e] >> NB_SHIFT], 1);
    __syncthreads();
    if (tid < n_buckets && lhist[tid] > 0)
        lbase[tid] = atomicAdd(&gcount[tid], lhist[tid]);
    else
        lbase[tid] = 0;
    __syncthreads();
    lhist[tid] = 0;   // reuse as running cursor
    __syncthreads();
    for (int i = tid; i < nv; i += 256) {
        int4 d4 = d4p[i];
        int4 s4 = s4p[i];
        {
            int b = d4.x >> NB_SHIFT;
            int off = lbase[b] + atomicAdd(&lhist[b], 1);
            if (off < CAP1)
                binned[(size_t)b * CAP1 + off] = (s4.x << NB_SHIFT) | (d4.x & (NODES_PER_B - 1));
        }
        {
            int b = d4.y >> NB_SHIFT;
            int off = lbase[b] + atomicAdd(&lhist[b], 1);
            if (off < CAP1)
                binned[(size_t)b * CAP1 + off] = (s4.y << NB_SHIFT) | (d4.y & (NODES_PER_B - 1));
        }
        {
            int b = d4.z >> NB_SHIFT;
            int off = lbase[b] + atomicAdd(&lhist[b], 1);
            if (off < CAP1)
                binned[(size_t)b * CAP1 + off] = (s4.z << NB_SHIFT) | (d4.z & (NODES_PER_B - 1));
        }
        {
            int b = d4.w >> NB_SHIFT;
            int off = lbase[b] + atomicAdd(&lhist[b], 1);
            if (off < CAP1)
                binned[(size_t)b * CAP1 + off] = (s4.w << NB_SHIFT) | (d4.w & (NODES_PER_B - 1));
        }
    }
    for (int e = beg + (nv << 2) + tid; e < end; e += 256) {
        int d = dst[e];
        int b = d >> NB_SHIFT;
        int off = lbase[b] + atomicAdd(&lhist[b], 1);
        if (off < CAP1)
            binned[(size_t)b * CAP1 + off] = (src[e] << NB_SHIFT) | (d & (NODES_PER_B - 1));
    }
}

// ---------------------------------------------------------------------------
// Pass 2: one block per bucket. Inline bucket-count scan -> base; local degree
// histogram -> LDS scan -> coalesced rowp + ssrc.
// ---------------------------------------------------------------------------
__global__ __launch_bounds__(256) void build_csr_kernel(
        const int* __restrict__ binned, const int* __restrict__ gcount,
        int* __restrict__ rowp, int* __restrict__ ssrc,
        int n_nodes, int n_buckets, int n_edges) {
    __shared__ int lhist[NODES_PER_B];
    __shared__ int lbase[NODES_PER_B];
    __shared__ int tmp[256];
    __shared__ int stage[CAP1];

    int b   = blockIdx.x;
    int tid = threadIdx.x;

    int v = (tid < n_buckets) ? min(gcount[tid], CAP1) : 0;
    tmp[tid] = v;
    __syncthreads();
    for (int off = 1; off < 256; off <<= 1) {
        int t = 0;
        if (tid >= off) t = tmp[tid - off];
        __syncthreads();
        if (tid >= off) tmp[tid] += t;
        __syncthreads();
    }
    int base = (b == 0) ? 0 : tmp[b - 1];
    int cnt  = min(gcount[b], CAP1);
    if (b == 0 && tid == 0) rowp[n_nodes] = n_edges;
    __syncthreads();

    int nodebase = b << NB_SHIFT;
    int nlocal   = min(NODES_PER_B, n_nodes - nodebase);
    const int* ebuf = binned + (size_t)b * CAP1;

    lhist[tid] = 0;
    lhist[tid + 256] = 0;
    __syncthreads();
    for (int i = tid; i < cnt; i += 256)
        atomicAdd(&lhist[ebuf[i] & (NODES_PER_B - 1)], 1);
    __syncthreads();

    int a0 = lhist[2 * tid];
    int a1 = lhist[2 * tid + 1];
    tmp[tid] = a0 + a1;
    __syncthreads();
    for (int off = 1; off < 256; off <<= 1) {
        int t = 0;
        if (tid >= off) t = tmp[tid - off];
        __syncthreads();
        if (tid >= off) tmp[tid] += t;
        __syncthreads();
    }
    int excl = tmp[tid] - (a0 + a1);
    lbase[2 * tid]     = excl;
    lbase[2 * tid + 1] = excl + a0;
    __syncthreads();

    for (int j = tid; j < nlocal; j += 256)
        rowp[nodebase + j] = base + lbase[j];

    lhist[tid] = 0;
    lhist[tid + 256] = 0;
    __syncthreads();

    for (int i = tid; i < cnt; i += 256) {
        int e  = ebuf[i];
        int ln = e & (NODES_PER_B - 1);
        int off = atomicAdd(&lhist[ln], 1);
        stage[lbase[ln] + off] = e >> NB_SHIFT;
    }
    __syncthreads();

    for (int i = tid; i < cnt; i += 256)
        ssrc[base + i] = stage[i];
}

// ---------------------------------------------------------------------------
// Mean aggregation v3 (proven best shape): wave per node, contiguous node
// chunk per wave. Lane = (row-group r = lane>>4, dim-quad c = lane&15).
// 16 edges/iter via 4 ushort4 gather loads in flight.
// ---------------------------------------------------------------------------
__global__ __launch_bounds__(256) void aggregate_bf16_kernel(
        const unsigned short* __restrict__ feat,
        const int* __restrict__ row_ptr,
        const int* __restrict__ sorted_src,
        unsigned short* __restrict__ mean_out,
        int n_nodes) {
    int lane = threadIdx.x & 63;
    int r    = lane >> 4;
    int c    = lane & 15;
    int wave   = (int)((blockIdx.x * blockDim.x + threadIdx.x) >> 6);
    int nwaves = (int)((gridDim.x * blockDim.x) >> 6);
    int npw  = (n_nodes + nwaves - 1) / nwaves;
    int nbeg = wave * npw;
    int nend = min(nbeg + npw, n_nodes);
    if (nbeg >= nend) return;

    int beg = row_ptr[nbeg];
    for (int node = nbeg; node < nend; ++node) {
        int end = row_ptr[node + 1];
        int endm1 = end - 1;
        float a0 = 0.f, a1 = 0.f, a2 = 0.f, a3 = 0.f;

        for (int i = beg; i < end; i += 16) {
            int e0 = i + r, e1 = i + 4 + r, e2 = i + 8 + r, e3 = i + 12 + r;
            int s0 = sorted_src[min(e0, endm1)];
            int s1 = sorted_src[min(e1, endm1)];
            int s2 = sorted_src[min(e2, endm1)];
            int s3 = sorted_src[min(e3, endm1)];
            ushort4 v0 = *(const ushort4*)(feat + ((size_t)s0 << 6) + (c << 2));
            ushort4 v1 = *(const ushort4*)(feat + ((size_t)s1 << 6) + (c << 2));
            ushort4 v2 = *(const ushort4*)(feat + ((size_t)s2 << 6) + (c << 2));
            ushort4 v3 = *(const ushort4*)(feat + ((size_t)s3 << 6) + (c << 2));
            if (e0 < end) {
                a0 += bf2f(v0.x); a1 += bf2f(v0.y);
                a2 += bf2f(v0.z); a3 += bf2f(v0.w);
            }
            if (e1 < end) {
                a0 += bf2f(v1.x); a1 += bf2f(v1.y);
                a2 += bf2f(v1.z); a3 += bf2f(v1.w);
            }
            if (e2 < end) {
                a0 += bf2f(v2.x); a1 += bf2f(v2.y);
                a2 += bf2f(v2.z); a3 += bf2f(v2.w);
            }
            if (e3 < end) {
                a0 += bf2f(v3.x); a1 += bf2f(v3.y);
                a2 += bf2f(v3.z); a3 += bf2f(v3.w);
            }
        }
        a0 += __shfl_xor(a0, 16); a1 += __shfl_xor(a1, 16);
        a2 += __shfl_xor(a2, 16); a3 += __shfl_xor(a3, 16);
        a0 += __shfl_xor(a0, 32); a1 += __shfl_xor(a1, 32);
        a2 += __shfl_xor(a2, 32); a3 += __shfl_xor(a3, 32);

        float inv = 1.0f / (float)max(end - beg, 1);
        if (r == 0) {
            ushort4 o;
            o.x = f2bf(a0 * inv); o.y = f2bf(a1 * inv);
            o.z = f2bf(a2 * inv); o.w = f2bf(a3 * inv);
            *(ushort4*)(mean_out + ((size_t)node << 6) + (c << 2)) = o;
        }
        beg = end;
    }
}

// ---------------------------------------------------------------------------
// Fused SAGE linear on MFMA: out = [relu]( mean @ Wl + xin @ Wr + b ), bf16 io.
// Grid sized so each wave handles exactly 2 tiles (balanced).
// ---------------------------------------------------------------------------
__global__ __launch_bounds__(256) void sage_linear_mfma_kernel(
        const unsigned short* __restrict__ mean,
        const unsigned short* __restrict__ xin,
        const unsigned short* __restrict__ pwl,
        const unsigned short* __restrict__ pwr,
        const float* __restrict__ bias,
        unsigned short* __restrict__ outp,
        int n_nodes, int do_relu) {
    int lane = threadIdx.x & 63;
    int wid  = threadIdx.x >> 6;
    int arow = lane & 15;
    int kgrp = lane >> 4;

    short8 wl[4][2], wr[4][2];
#pragma unroll
    for (int ct = 0; ct < 4; ++ct)
#pragma unroll
        for (int kk = 0; kk < 2; ++kk) {
            wl[ct][kk] = *(const short8*)(pwl + (((ct * 2 + kk) * 64 + lane) << 3));
            wr[ct][kk] = *(const short8*)(pwr + (((ct * 2 + kk) * 64 + lane) << 3));
        }
    float bj[4];
#pragma unroll
    for (int ct = 0; ct < 4; ++ct) bj[ct] = bias[ct * 16 + arow];

    int wave   = blockIdx.x * 4 + wid;
    int nwaves = gridDim.x * 4;
    int ntiles = (n_nodes + 15) >> 4;

    for (int t = wave; t < ntiles; t += nwaves) {
        int base = t * 16;
        int lrow = base + arow;
        if (lrow >= n_nodes) lrow = n_nodes - 1;
        const unsigned short* mrow = mean + (size_t)lrow * D + kgrp * 8;
        const unsigned short* xrow = xin  + (size_t)lrow * D + kgrp * 8;
        short8 am0 = *(const short8*)(mrow);
        short8 am1 = *(const short8*)(mrow + 32);
        short8 ax0 = *(const short8*)(xrow);
        short8 ax1 = *(const short8*)(xrow + 32);

#pragma unroll
        for (int ct = 0; ct < 4; ++ct) {
            f32x4 acc = {0.f, 0.f, 0.f, 0.f};
            acc = __builtin_amdgcn_mfma_f32_16x16x32_bf16(am0, wl[ct][0], acc, 0, 0, 0);
            acc = __builtin_amdgcn_mfma_f32_16x16x32_bf16(am1, wl[ct][1], acc, 0, 0, 0);
            acc = __builtin_amdgcn_mfma_f32_16x16x32_bf16(ax0, wr[ct][0], acc, 0, 0, 0);
            acc = __builtin_amdgcn_mfma_f32_16x16x32_bf16(ax1, wr[ct][1], acc, 0, 0, 0);
            int col = ct * 16 + arow;
#pragma unroll
            for (int rr = 0; rr < 4; ++rr) {
                int row = base + kgrp * 4 + rr;
                float v = acc[rr] + bj[ct];
                if (do_relu) v = fmaxf(v, 0.0f);
                if (row < n_nodes) outp[(size_t)row * D + col] = f2bf(v);
            }
        }
    }
}

// ---------------------------------------------------------------------------
// Edge decode: 16-lane group per edge, FOUR edges per group per iteration
// (16 edges/wave-iter, 8 row loads in flight per lane). All loaded edges are
// useful (no clamp waste except the final iteration).
// ---------------------------------------------------------------------------
__global__ __launch_bounds__(256) void decode_bf16_kernel(
        const unsigned short* __restrict__ z,
        const int* __restrict__ esrc,
        const int* __restrict__ edst,
        float* __restrict__ out,
        int n) {
    int lane = threadIdx.x & 63;
    int g    = lane >> 4;
    int c    = lane & 15;
    int wave   = (int)((blockIdx.x * blockDim.x + threadIdx.x) >> 6);
    int nwaves = (int)((gridDim.x * blockDim.x) >> 6);
    int niter  = (n + 15) >> 4;

    for (int it = wave; it < niter; it += nwaves) {
        int e0 = it * 16 + g;
        int e1 = it * 16 + 4 + g;
        int e2 = it * 16 + 8 + g;
        int e3 = it * 16 + 12 + g;
        int ec0 = min(e0, n - 1), ec1 = min(e1, n - 1);
        int ec2 = min(e2, n - 1), ec3 = min(e3, n - 1);
        int s0 = esrc[ec0], d0 = edst[ec0];
        int s1 = esrc[ec1], d1 = edst[ec1];
        int s2 = esrc[ec2], d2 = edst[ec2];
        int s3 = esrc[ec3], d3 = edst[ec3];
        ushort4 vs0 = *(const ushort4*)(z + ((size_t)s0 << 6) + (c << 2));
        ushort4 vd0 = *(const ushort4*)(z + ((size_t)d0 << 6) + (c << 2));
        ushort4 vs1 = *(const ushort4*)(z + ((size_t)s1 << 6) + (c << 2));
        ushort4 vd1 = *(const ushort4*)(z + ((size_t)d1 << 6) + (c << 2));
        ushort4 vs2 = *(const ushort4*)(z + ((size_t)s2 << 6) + (c << 2));
        ushort4 vd2 = *(const ushort4*)(z + ((size_t)d2 << 6) + (c << 2));
        ushort4 vs3 = *(const ushort4*)(z + ((size_t)s3 << 6) + (c << 2));
        ushort4 vd3 = *(const ushort4*)(z + ((size_t)d3 << 6) + (c << 2));
        float p0 = bf2f(vs0.x) * bf2f(vd0.x) + bf2f(vs0.y) * bf2f(vd0.y) +
                   bf2f(vs0.z) * bf2f(vd0.z) + bf2f(vs0.w) * bf2f(vd0.w);
        float p1 = bf2f(vs1.x) * bf2f(vd1.x) + bf2f(vs1.y) * bf2f(vd1.y) +
                   bf2f(vs1.z) * bf2f(vd1.z) + bf2f(vs1.w) * bf2f(vd1.w);
        float p2 = bf2f(vs2.x) * bf2f(vd2.x) + bf2f(vs2.y) * bf2f(vd2.y) +
                   bf2f(vs2.z) * bf2f(vd2.z) + bf2f(vs2.w) * bf2f(vd2.w);
        float p3 = bf2f(vs3.x) * bf2f(vd3.x) + bf2f(vs3.y) * bf2f(vd3.y) +
                   bf2f(vs3.z) * bf2f(vd3.z) + bf2f(vs3.w) * bf2f(vd3.w);
        p0 += __shfl_xor(p0, 1);  p1 += __shfl_xor(p1, 1);
        p2 += __shfl_xor(p2, 1);  p3 += __shfl_xor(p3, 1);
        p0 += __shfl_xor(p0, 2);  p1 += __shfl_xor(p1, 2);
        p2 += __shfl_xor(p2, 2);  p3 += __shfl_xor(p3, 2);
        p0 += __shfl_xor(p0, 4);  p1 += __shfl_xor(p1, 4);
        p2 += __shfl_xor(p2, 4);  p3 += __shfl_xor(p3, 4);
        p0 += __shfl_xor(p0, 8);  p1 += __shfl_xor(p1, 8);
        p2 += __shfl_xor(p2, 8);  p3 += __shfl_xor(p3, 8);
        if (c == 0) {
            if (e0 < n) out[e0] = p0;
            if (e1 < n) out[e1] = p1;
            if (e2 < n) out[e2] = p2;
            if (e3 < n) out[e3] = p3;
        }
    }
}

extern "C" void kernel_launch(void* const* d_in, const int* in_sizes, int n_in,
                              void* d_out, int out_size, void* d_ws, size_t ws_size,
                              hipStream_t stream) {
    const float* x   = (const float*)d_in[0];
    const int*   ei  = (const int*)d_in[1];   // [2, E]: src row then dst row
    const int*   eli = (const int*)d_in[2];   // [2, L]
    const float* W1l = (const float*)d_in[3];
    const float* W1r = (const float*)d_in[4];
    const float* b1  = (const float*)d_in[5];
    const float* W2l = (const float*)d_in[6];
    const float* W2r = (const float*)d_in[7];
    const float* b2  = (const float*)d_in[8];
    float* out = (float*)d_out;

    const int n_nodes = in_sizes[0] / D;
    const int n_edges = in_sizes[1] / 2;
    const int n_label = in_sizes[2] / 2;
    const int n_buckets = (n_nodes + NODES_PER_B - 1) >> NB_SHIFT;

    const int* e_src = ei;
    const int* e_dst = ei + n_edges;
    const int* l_src = eli;
    const int* l_dst = eli + n_label;

    // Workspace layout:
    //   xb, meanb, h, z : N*64 ushort each
    //   rowp : N+1 ints; ssrc : E + 8 ints
    //   gcount : 256 ints; pw : 4*4096 ushort
    //   binned (packed ints, ~9.6 MB) aliases h (dead until L1 linear writes h)
    unsigned short* xb    = (unsigned short*)d_ws;
    unsigned short* meanb = xb + (size_t)n_nodes * D;
    unsigned short* h     = meanb + (size_t)n_nodes * D;
    unsigned short* z     = h + (size_t)n_nodes * D;
    int* rowp   = (int*)(z + (size_t)n_nodes * D);
    int* ssrc   = rowp + (n_nodes + 1);
    int* gcount = ssrc + n_edges + 8;
    unsigned short* pw = (unsigned short*)(gcount + 256);
    unsigned short* pw1l = pw;
    unsigned short* pw1r = pw + 4096;
    unsigned short* pw2l = pw + 8192;
    unsigned short* pw2r = pw + 12288;
    int* binned = (int*)h;

    dim3 blk(256);
    dim3 grd_nodes(2048);
    dim3 grd_linear(782);   // 3128 waves x 2 tiles = 6256 >= 6250 tiles, balanced
    dim3 grd_decode(1563);  // 6252 waves x ~2 iters over 12500 decode groups

    // ---- Prep (convert + pack + gcount zero) ----
    prep_kernel<<<dim3(2048), blk, 0, stream>>>(x, xb, n_nodes * D / 4,
                                                W1l, W1r, W2l, W2r, pw, gcount);

    // ---- CSR build ----
    bin_edges_kernel<<<dim3(512), blk, 0, stream>>>(e_src, e_dst, gcount, binned,
                                                    n_edges, n_buckets);
    build_csr_kernel<<<dim3(n_buckets), blk, 0, stream>>>(binned, gcount, rowp,
                                                          ssrc, n_nodes,
                                                          n_buckets, n_edges);

    // ---- Layer 1 ----
    aggregate_bf16_kernel<<<grd_nodes, blk, 0, stream>>>(xb, rowp, ssrc, meanb, n_nodes);
    sage_linear_mfma_kernel<<<grd_linear, blk, 0, stream>>>(meanb, xb, pw1l, pw1r, b1,
                                                            h, n_nodes, /*relu=*/1);

    // ---- Layer 2 ----
    aggregate_bf16_kernel<<<grd_nodes, blk, 0, stream>>>(h, rowp, ssrc, meanb, n_nodes);
    sage_linear_mfma_kernel<<<grd_linear, blk, 0, stream>>>(meanb, h, pw2l, pw2r, b2,
                                                            z, n_nodes, /*relu=*/0);

    // ---- Decode ----
    decode_bf16_kernel<<<grd_decode, blk, 0, stream>>>(z, l_src, l_dst, out, n_label);
}